// Round 10
// baseline (387.697 us; speedup 1.0000x reference)
//
#include <hip/hip_runtime.h>

typedef unsigned short u16;
typedef unsigned int   u32;
typedef __bf16 bf16x8 __attribute__((ext_vector_type(8)));   // MFMA A/B (4 VGPRs)
typedef float  f32x16 __attribute__((ext_vector_type(16)));  // MFMA C/D 32x32

#define BH    16
#define NSEQ  4096
#define DIM   64
#define BM    128           // Q rows per block (4 waves x 32 rows, dup across halves)
#define BN    64            // K rows per tile
#define LDP   72            // K/V/W LDS row stride (u16)
#define NTH   32            // K-tiles per half (2 halves x 32 = 64)
#define QTILES (NSEQ / BM)  // 32

// smem carve (u16): sK [2][64*72] | sV [2][64*72] | sW [64*72] | lX f32[256]
#define SK_OFF   0
#define SV_OFF   9216
#define SW_OFF   18432
#define LX_OFF   23040
#define SMEM_U16 23552      // 47104 B
#define HBUF     4608       // one half's K or V buffer (64*72)
// epilogue overlay: outS f32[64][133] at smem base = 34048 B (< SW_OFF*2=36864 B)

#define MFMA __builtin_amdgcn_mfma_f32_32x32x16_bf16

__device__ __forceinline__ float bf2f(u16 u) {
    union { u32 i; float f; } v; v.i = ((u32)u) << 16; return v.f;
}
__device__ __forceinline__ u16 f2bf(float f) {          // true RNE
    union { float f; u32 i; } v; v.f = f;
    u32 r = v.i + 0x7fffu + ((v.i >> 16) & 1u);
    return (u16)(r >> 16);
}
#if __has_builtin(__builtin_amdgcn_exp2f)
__device__ __forceinline__ float exp2_raw(float x) { return __builtin_amdgcn_exp2f(x); }
#else
__device__ __forceinline__ float exp2_raw(float x) {
    float r; asm("v_exp_f32 %0, %1" : "=v"(r) : "v"(x)); return r;
}
#endif
// packed f32->bf16 (RNE), low16 = a, high16 = b
__device__ __forceinline__ u32 cvtpk(float a, float b) {
    u32 r; asm("v_cvt_pk_bf16_f32 %0, %1, %2" : "=v"(r) : "v"(a), "v"(b)); return r;
}
// v_permlane32_swap_b32: a.hi(lanes 32-63) <-> b.lo(lanes 0-31)
__device__ __forceinline__ void plswap(u32& a, u32& b) {
    asm("v_permlane32_swap_b32 %0, %1" : "+v"(a), "+v"(b));
}
// LDS-only barrier: order ds ops across waves WITHOUT draining vmcnt.
__device__ __forceinline__ void lds_barrier() {
    asm volatile("s_waitcnt lgkmcnt(0)\n\ts_barrier" ::: "memory");
}
// load 8 bf16 and scale by s (f32 precision), repack to bf16x8 (hoisted, 1x)
__device__ __forceinline__ bf16x8 ldq_scaled(const u16* p, float s) {
    union { u32 u[4]; bf16x8 v; } r;
#pragma unroll
    for (int i = 0; i < 4; i++)
        r.u[i] = cvtpk(bf2f(p[2*i]) * s, bf2f(p[2*i+1]) * s);
    return r.v;
}

// ---------------------------------------------------------------------------
// prep_norm: read x (fp32) once; write xn = bf16(L2-normalized rows) and
// xr = bf16(raw rows). Pure streaming, no LDS. 1024 blocks.
// ---------------------------------------------------------------------------
__global__ __launch_bounds__(256) void ContentGCN_5059471475267_prepn(
    const float* __restrict__ src, u16* __restrict__ xn, u16* __restrict__ xr)
{
    int gid = blockIdx.x * 256 + threadIdx.x;
    int row = gid >> 2, cg = (gid & 3) * 16;
    size_t base = (size_t)row * DIM + cg;

    float v[16];
    const float4* g = (const float4*)(src + base);
#pragma unroll
    for (int i = 0; i < 4; i++) {
        float4 t = g[i];
        v[4*i] = t.x; v[4*i+1] = t.y; v[4*i+2] = t.z; v[4*i+3] = t.w;
    }
    float ss = 0.f;
#pragma unroll
    for (int d = 0; d < 16; d++) ss += v[d] * v[d];
    ss += __shfl_xor(ss, 1);
    ss += __shfl_xor(ss, 2);                        // full 64-elem row sum
    float n = sqrtf(ss);
    if (n < 1e-12f) n = 1e-12f;                     // F.normalize eps
    float inv = 1.0f / n;

    alignas(16) u16 nb[16], rb[16];
#pragma unroll
    for (int d = 0; d < 16; d++) { nb[d] = f2bf(v[d] * inv); rb[d] = f2bf(v[d]); }
    uint4* gn = (uint4*)(xn + base);
    gn[0] = ((uint4*)nb)[0]; gn[1] = ((uint4*)nb)[1];
    uint4* gr = (uint4*)(xr + base);
    gr[0] = ((uint4*)rb)[0]; gr[1] = ((uint4*)rb)[1];
}

// ---------------------------------------------------------------------------
// attn: 32x32x16 MFMA flash attention, in-register softmax (swapped QK^T +
// cvt_pk/permlane), V transposed during staging (rotation-swizzled scatter).
// REG-PV SCHEDULE (in-order-DS-correct, fixes R9): per tile:
//   [barrier: publish K(t),V(t)] -> S-batch (K reads) ->
//   read ALL 8 V fragments into regs -> [barrier: buffers free] ->
//   staging writes K(t+1)/V(t+1) + issue t+2 loads -> softmax+PV (regs only).
// The staging writes are issued but NOT waited on until the next tile's
// barrier — they overlap the ~600-cy softmax+PV. (R9 failed because PV's
// V-reads were issued AFTER the writes: in-order DS made them drain behind
// the staging queue. Reads-before-writes is the correct order.)
// Q pre-scaled by `scale` so softmax is a bare exp2 (2^scale cancels in O/l).
// ---------------------------------------------------------------------------
__global__ __launch_bounds__(512, 4) void ContentGCN_5059471475267_attn(
    const u16* __restrict__ xn, const u16* __restrict__ vsrc,
    const void* __restrict__ res, int res_isf,
    const float* __restrict__ Wt, const float* __restrict__ alphap,
    void* __restrict__ outp, int out_isf, u16* __restrict__ xnout)
{
    __shared__ u16 smem[SMEM_U16];
    u16* sK = smem + SK_OFF;
    u16* sV = smem + SV_OFF;
    u16* sW = smem + SW_OFF;
    float* lX = (float*)(smem + LX_OFF);

    int tid  = threadIdx.x;
    int w    = tid >> 6, lane = tid & 63;
    int half = w >> 2,  wv   = w & 3;
    int l31  = lane & 31, hi = lane >> 5;
    int bh   = blockIdx.x >> 5;
    int qt   = blockIdx.x & 31;

    float scale = 1.4426950408889634f / fmaxf(alphap[0], 0.01f);  // exp2 domain

    // stage W once: sW[e*LDP + d] = bf16(W[e][d]); 512 thr cover 64x64
    {
        int rr = tid >> 3, c0 = (tid & 7) * 8;
        const float4* gw = (const float4*)(Wt + rr * DIM + c0);
        float4 t0 = gw[0], t1 = gw[1];
        alignas(16) u16 wb[8];
        wb[0] = f2bf(t0.x); wb[1] = f2bf(t0.y); wb[2] = f2bf(t0.z); wb[3] = f2bf(t0.w);
        wb[4] = f2bf(t1.x); wb[5] = f2bf(t1.y); wb[6] = f2bf(t1.z); wb[7] = f2bf(t1.w);
        *(uint4*)&sW[rr * LDP + c0] = *(const uint4*)wb;
    }

    // Q as MFMA B-fragments, PRE-SCALED by `scale` (col=q=l31, k=d)
    int qrow = qt * BM + wv * 32 + l31;
    const u16* qp = xn + ((size_t)bh * NSEQ + qrow) * DIM + hi * 8;
    bf16x8 bQ0 = ldq_scaled(qp,      scale);
    bf16x8 bQ1 = ldq_scaled(qp + 16, scale);
    bf16x8 bQ2 = ldq_scaled(qp + 32, scale);
    bf16x8 bQ3 = ldq_scaled(qp + 48, scale);

    f32x16 z16;
#pragma unroll
    for (int i = 0; i < 16; i++) z16[i] = 0.f;
    f32x16 OT0 = z16, OT1 = z16;      // O^T: d-blocks 0/1, col=q
    float la0 = 0.f, la1 = 0.f, la2 = 0.f, la3 = 0.f;

    u16* sKh = sK + half * HBUF;
    u16* sVh = sV + half * HBUF;

    int ltid = tid & 255;
    int srow = ltid >> 2, scol = (ltid & 3) * 16;   // per-half staging
    int nl   = (srow + ((ltid & 3) << 4)) & 63;     // rotated n-index

    const u16* pk = xn   + ((size_t)bh * NSEQ + half * (NTH * BN) + srow) * DIM + scol;
    const u16* pv = vsrc + ((size_t)bh * NSEQ + half * (NTH * BN) + srow) * DIM + scol;

    const u16* kB = sKh + l31 * LDP + hi * 8;          // K A-frag base

    // V^T read bases + per-lane rotated n-offsets
    int g  = l31 >> 4;
    int r0 = ((g)     & 3) << 4;
    int r1 = ((g + 1) & 3) << 4;
    int r2 = ((g + 2) & 3) << 4;
    int r3 = ((g + 3) & 3) << 4;
    const u16* vA = sVh + l31 * LDP + hi * 8;          // d-block 0
    const u16* vB = sVh + (32 + l31) * LDP + hi * 8;   // d-block 1

    // --- prologue: stage tile 0; load tile 1 into regs ---
    uint4 ck0 = ((const uint4*)pk)[0], ck1 = ((const uint4*)pk)[1];
    uint4 cv0 = ((const uint4*)pv)[0], cv1 = ((const uint4*)pv)[1];
    pk += (size_t)BN * DIM; pv += (size_t)BN * DIM;
    *(uint4*)&sKh[srow * LDP + scol]     = ck0;
    *(uint4*)&sKh[srow * LDP + scol + 8] = ck1;
    {
        alignas(16) u16 vb[16];
        ((uint4*)vb)[0] = cv0; ((uint4*)vb)[1] = cv1;
#pragma unroll
        for (int j = 0; j < 16; j++) sVh[(scol + j) * LDP + nl] = vb[j];
    }
    ck0 = ((const uint4*)pk)[0]; ck1 = ((const uint4*)pk)[1];
    cv0 = ((const uint4*)pv)[0]; cv1 = ((const uint4*)pv)[1];
    pk += (size_t)BN * DIM; pv += (size_t)BN * DIM;

    for (int kt = 0; kt < NTH; kt++) {
        lds_barrier();     // publish K(kt), V(kt)

        // --- S-batch: ALL K reads (both kb) ---
        const u16* kb1 = kB + 32 * LDP;
        f32x16 ST0, ST1;
        __builtin_amdgcn_s_setprio(1);
        ST0 = MFMA(*(const bf16x8*)(kB),       bQ0, z16, 0, 0, 0);
        ST0 = MFMA(*(const bf16x8*)(kB + 16),  bQ1, ST0, 0, 0, 0);
        ST0 = MFMA(*(const bf16x8*)(kB + 32),  bQ2, ST0, 0, 0, 0);
        ST0 = MFMA(*(const bf16x8*)(kB + 48),  bQ3, ST0, 0, 0, 0);
        ST1 = MFMA(*(const bf16x8*)(kb1),      bQ0, z16, 0, 0, 0);
        ST1 = MFMA(*(const bf16x8*)(kb1 + 16), bQ1, ST1, 0, 0, 0);
        ST1 = MFMA(*(const bf16x8*)(kb1 + 32), bQ2, ST1, 0, 0, 0);
        ST1 = MFMA(*(const bf16x8*)(kb1 + 48), bQ3, ST1, 0, 0, 0);
        __builtin_amdgcn_s_setprio(0);

        // --- V fragments -> registers (reads BEFORE any staging writes) ---
        bf16x8 vf0 = *(const bf16x8*)(vA + r0);
        bf16x8 vf1 = *(const bf16x8*)(vA + r1);
        bf16x8 vf2 = *(const bf16x8*)(vA + r2);
        bf16x8 vf3 = *(const bf16x8*)(vA + r3);
        bf16x8 vf4 = *(const bf16x8*)(vB + r0);
        bf16x8 vf5 = *(const bf16x8*)(vB + r1);
        bf16x8 vf6 = *(const bf16x8*)(vB + r2);
        bf16x8 vf7 = *(const bf16x8*)(vB + r3);

        lds_barrier();     // all reads done -> K and V buffers free

        // --- staging writes tile kt+1 + issue tile kt+2 loads (overlap) ---
        if (kt + 1 < NTH) {
            *(uint4*)&sKh[srow * LDP + scol]     = ck0;
            *(uint4*)&sKh[srow * LDP + scol + 8] = ck1;
            alignas(16) u16 vb[16];
            ((uint4*)vb)[0] = cv0; ((uint4*)vb)[1] = cv1;
#pragma unroll
            for (int j = 0; j < 16; j++) sVh[(scol + j) * LDP + nl] = vb[j];
            if (kt + 2 < NTH) {
                ck0 = ((const uint4*)pk)[0]; ck1 = ((const uint4*)pk)[1];
                cv0 = ((const uint4*)pv)[0]; cv1 = ((const uint4*)pv)[1];
                pk += (size_t)BN * DIM; pv += (size_t)BN * DIM;
            }
        }

        // --- softmax kb0 + PV kb0 (registers only) ---
        {
            float p0  = exp2_raw(ST0[0]);
            float p1  = exp2_raw(ST0[1]);
            float p2  = exp2_raw(ST0[2]);
            float p3  = exp2_raw(ST0[3]);
            float p4  = exp2_raw(ST0[4]);
            float p5  = exp2_raw(ST0[5]);
            float p6  = exp2_raw(ST0[6]);
            float p7  = exp2_raw(ST0[7]);
            float p8  = exp2_raw(ST0[8]);
            float p9  = exp2_raw(ST0[9]);
            float p10 = exp2_raw(ST0[10]);
            float p11 = exp2_raw(ST0[11]);
            float p12 = exp2_raw(ST0[12]);
            float p13 = exp2_raw(ST0[13]);
            float p14 = exp2_raw(ST0[14]);
            float p15 = exp2_raw(ST0[15]);
            u32 w0 = cvtpk(p0,  p1),  w1 = cvtpk(p2,  p3);
            u32 w2 = cvtpk(p4,  p5),  w3 = cvtpk(p6,  p7);
            u32 w4 = cvtpk(p8,  p9),  w5 = cvtpk(p10, p11);
            u32 w6 = cvtpk(p12, p13), w7 = cvtpk(p14, p15);
            plswap(w0, w2); plswap(w1, w3);
            plswap(w4, w6); plswap(w5, w7);
            union { u32 u[4]; bf16x8 v; } bp0, bp1;
            bp0.u[0] = w0; bp0.u[1] = w1; bp0.u[2] = w2; bp0.u[3] = w3;  // k [0,16)
            bp1.u[0] = w4; bp1.u[1] = w5; bp1.u[2] = w6; bp1.u[3] = w7;  // k [16,32)
            __builtin_amdgcn_s_setprio(1);
            OT0 = MFMA(vf0, bp0.v, OT0, 0, 0, 0);
            OT0 = MFMA(vf1, bp1.v, OT0, 0, 0, 0);
            OT1 = MFMA(vf6, bp0.v, OT1, 0, 0, 0);
            OT1 = MFMA(vf7, bp1.v, OT1, 0, 0, 0);
            __builtin_amdgcn_s_setprio(0);
            la0 += (p0 + p4) + (p8  + p12);
            la1 += (p1 + p5) + (p9  + p13);
            la2 += (p2 + p6) + (p10 + p14);
            la3 += (p3 + p7) + (p11 + p15);
        }

        // --- softmax kb1 + PV kb1 (registers only) ---
        {
            float p0  = exp2_raw(ST1[0]);
            float p1  = exp2_raw(ST1[1]);
            float p2  = exp2_raw(ST1[2]);
            float p3  = exp2_raw(ST1[3]);
            float p4  = exp2_raw(ST1[4]);
            float p5  = exp2_raw(ST1[5]);
            float p6  = exp2_raw(ST1[6]);
            float p7  = exp2_raw(ST1[7]);
            float p8  = exp2_raw(ST1[8]);
            float p9  = exp2_raw(ST1[9]);
            float p10 = exp2_raw(ST1[10]);
            float p11 = exp2_raw(ST1[11]);
            float p12 = exp2_raw(ST1[12]);
            float p13 = exp2_raw(ST1[13]);
            float p14 = exp2_raw(ST1[14]);
            float p15 = exp2_raw(ST1[15]);
            u32 w0 = cvtpk(p0,  p1),  w1 = cvtpk(p2,  p3);
            u32 w2 = cvtpk(p4,  p5),  w3 = cvtpk(p6,  p7);
            u32 w4 = cvtpk(p8,  p9),  w5 = cvtpk(p10, p11);
            u32 w6 = cvtpk(p12, p13), w7 = cvtpk(p14, p15);
            plswap(w0, w2); plswap(w1, w3);
            plswap(w4, w6); plswap(w5, w7);
            union { u32 u[4]; bf16x8 v; } bp0, bp1;
            bp0.u[0] = w0; bp0.u[1] = w1; bp0.u[2] = w2; bp0.u[3] = w3;
            bp1.u[0] = w4; bp1.u[1] = w5; bp1.u[2] = w6; bp1.u[3] = w7;
            __builtin_amdgcn_s_setprio(1);
            OT0 = MFMA(vf2, bp0.v, OT0, 0, 0, 0);
            OT0 = MFMA(vf3, bp1.v, OT0, 0, 0, 0);
            OT1 = MFMA(vf4, bp0.v, OT1, 0, 0, 0);
            OT1 = MFMA(vf5, bp1.v, OT1, 0, 0, 0);
            __builtin_amdgcn_s_setprio(0);
            la0 += (p0 + p4) + (p8  + p12);
            la1 += (p1 + p5) + (p9  + p13);
            la2 += (p2 + p6) + (p10 + p14);
            la3 += (p3 + p7) + (p11 + p15);
        }
    }

    // ---- l: intra-wave hi/lo merge, then cross-half exchange (tiny) ----
    float lsum = (la0 + la1) + (la2 + la3);
    u32 ja = __float_as_uint(lsum), jb = ja;
    plswap(ja, jb);
    float lfull = __uint_as_float(ja) + __uint_as_float(jb);  // full K-half sum

    __syncthreads();                                  // all loop LDS ops done
    if (lane < 32) lX[w * 32 + l31] = lfull;
    __syncthreads();
    float invl = 1.0f / (lfull + lX[(w ^ 4) * 32 + l31]);

    // ---- av^T -> bf16 B-frags over d-chunks (same cvt_pk+permlane recipe) ----
    union { u32 u[4]; bf16x8 v; } av0, av1, av2, av3;
    {
        u32 x0 = cvtpk(OT0[0]  * invl, OT0[1]  * invl), x1 = cvtpk(OT0[2]  * invl, OT0[3]  * invl);
        u32 x2 = cvtpk(OT0[4]  * invl, OT0[5]  * invl), x3 = cvtpk(OT0[6]  * invl, OT0[7]  * invl);
        u32 x4 = cvtpk(OT0[8]  * invl, OT0[9]  * invl), x5 = cvtpk(OT0[10] * invl, OT0[11] * invl);
        u32 x6 = cvtpk(OT0[12] * invl, OT0[13] * invl), x7 = cvtpk(OT0[14] * invl, OT0[15] * invl);
        plswap(x0, x2); plswap(x1, x3); plswap(x4, x6); plswap(x5, x7);
        av0.u[0] = x0; av0.u[1] = x1; av0.u[2] = x2; av0.u[3] = x3;  // d [0,16)
        av1.u[0] = x4; av1.u[1] = x5; av1.u[2] = x6; av1.u[3] = x7;  // d [16,32)
        u32 y0 = cvtpk(OT1[0]  * invl, OT1[1]  * invl), y1 = cvtpk(OT1[2]  * invl, OT1[3]  * invl);
        u32 y2 = cvtpk(OT1[4]  * invl, OT1[5]  * invl), y3 = cvtpk(OT1[6]  * invl, OT1[7]  * invl);
        u32 y4 = cvtpk(OT1[8]  * invl, OT1[9]  * invl), y5 = cvtpk(OT1[10] * invl, OT1[11] * invl);
        u32 y6 = cvtpk(OT1[12] * invl, OT1[13] * invl), y7 = cvtpk(OT1[14] * invl, OT1[15] * invl);
        plswap(y0, y2); plswap(y1, y3); plswap(y4, y6); plswap(y5, y7);
        av2.u[0] = y0; av2.u[1] = y1; av2.u[2] = y2; av2.u[3] = y3;  // d [32,48)
        av3.u[0] = y4; av3.u[1] = y5; av3.u[2] = y6; av3.u[3] = y7;  // d [48,64)
    }

    // ---- out^T partial = W * av^T (per K-half; linear, so halves sum) ----
    f32x16 R0, R1;
    {
        const u16* w0p = sW + l31 * LDP + hi * 8;          // e-block 0
        const u16* w1p = sW + (32 + l31) * LDP + hi * 8;   // e-block 1
        R0 = MFMA(*(const bf16x8*)(w0p),      av0.v, z16, 0, 0, 0);
        R0 = MFMA(*(const bf16x8*)(w0p + 16), av1.v, R0,  0, 0, 0);
        R0 = MFMA(*(const bf16x8*)(w0p + 32), av2.v, R0,  0, 0, 0);
        R0 = MFMA(*(const bf16x8*)(w0p + 48), av3.v, R0,  0, 0, 0);
        R1 = MFMA(*(const bf16x8*)(w1p),      av0.v, z16, 0, 0, 0);
        R1 = MFMA(*(const bf16x8*)(w1p + 16), av1.v, R1,  0, 0, 0);
        R1 = MFMA(*(const bf16x8*)(w1p + 32), av2.v, R1,  0, 0, 0);
        R1 = MFMA(*(const bf16x8*)(w1p + 48), av3.v, R1,  0, 0, 0);
    }

    // ---- merge halves in f32 LDS outS[e][133] (overlays sK/sV) ----
    float* outS = (float*)smem;
    if (half == 0) {
#pragma unroll
        for (int r = 0; r < 16; r++) {
            int e0 = (r & 3) + 8 * (r >> 2) + 4 * hi;
            outS[e0 * 133 + wv * 32 + l31]        = R0[r];
            outS[(e0 + 32) * 133 + wv * 32 + l31] = R1[r];
        }
    }
    __syncthreads();
    if (half == 1) {
#pragma unroll
        for (int r = 0; r < 16; r++) {
            int e0 = (r & 3) + 8 * (r >> 2) + 4 * hi;
            outS[e0 * 133 + wv * 32 + l31]        += R0[r];
            outS[(e0 + 32) * 133 + wv * 32 + l31] += R1[r];
        }
    }
    __syncthreads();

    // ---- residual + relu + coalesced store (+ fused next-layer normalize) ----
    {
        int q = tid >> 2, c = tid & 3;
        size_t gbase = ((size_t)bh * NSEQ + qt * BM + q) * DIM + c * 16;
        float vv[16];
#pragma unroll
        for (int j = 0; j < 16; j++) vv[j] = outS[(c * 16 + j) * 133 + q];
        if (res_isf) {
            const float4* rp = (const float4*)((const float*)res + gbase);
#pragma unroll
            for (int i = 0; i < 4; i++) {
                float4 t = rp[i];
                vv[4*i] += t.x; vv[4*i+1] += t.y; vv[4*i+2] += t.z; vv[4*i+3] += t.w;
            }
        } else {
            alignas(16) u16 rb[16];
            const uint4* rp = (const uint4*)((const u16*)res + gbase);
            ((uint4*)rb)[0] = rp[0]; ((uint4*)rb)[1] = rp[1];
#pragma unroll
            for (int j = 0; j < 16; j++) vv[j] += bf2f(rb[j]);
        }
#pragma unroll
        for (int j = 0; j < 16; j++) vv[j] = (vv[j] < 0.f) ? 0.f : vv[j];  // NaN-transparent
        if (out_isf) {
            float4* op = (float4*)((float*)outp + gbase);
#pragma unroll
            for (int i = 0; i < 4; i++)
                op[i] = make_float4(vv[4*i], vv[4*i+1], vv[4*i+2], vv[4*i+3]);
        } else {
            alignas(16) u16 ob[16];
#pragma unroll
            for (int j = 0; j < 16; j++) ob[j] = f2bf(vv[j]);
            uint4* op = (uint4*)((u16*)outp + gbase);
            op[0] = ((uint4*)ob)[0]; op[1] = ((uint4*)ob)[1];
        }
        if (xnout) {   // fused next-layer prep: L2-normalize the output row
            float ss = 0.f;
#pragma unroll
            for (int j = 0; j < 16; j++) ss += vv[j] * vv[j];
            ss += __shfl_xor(ss, 1);
            ss += __shfl_xor(ss, 2);                 // 4 lanes/row -> full row
            float n = sqrtf(ss);
            if (n < 1e-12f) n = 1e-12f;
            float inv = 1.0f / n;
            alignas(16) u16 nb[16];
#pragma unroll
            for (int j = 0; j < 16; j++) nb[j] = f2bf(vv[j] * inv);
            uint4* gn = (uint4*)(xnout + gbase);
            gn[0] = ((uint4*)nb)[0]; gn[1] = ((uint4*)nb)[1];
        }
    }
}

extern "C" void kernel_launch(void* const* d_in, const int* in_sizes, int n_in,
                              void* d_out, int out_size, void* d_ws, size_t ws_size,
                              hipStream_t stream) {
    const float* x  = (const float*)d_in[0];
    const float* W1 = (const float*)d_in[1];
    const float* W2 = (const float*)d_in[2];
    const float* a1 = (const float*)d_in[3];
    const float* a2 = (const float*)d_in[4];
    float* outp = (float*)d_out;

    size_t elems = (size_t)BH * NSEQ * DIM;        // 4,194,304
    u16* xn1 = (u16*)d_ws;                         // 8.39 MB normalized (L1)
    u16* xr  = xn1 + elems;                        // 8.39 MB raw bf16 x
    u16* xn2 = xr + elems;                         // 8.39 MB normalized (L2, fused)
    u16* y1  = xn2 + elems;                        // 8.39 MB layer-1 out (bf16)

    dim3 pgrid(1024), pblk(256);
    dim3 agrid(BH * QTILES), ablk(512);

    // layer 1: normalize (xn1) + raw bf16 copy (xr); attn stages V from xr
    ContentGCN_5059471475267_prepn<<<pgrid, pblk, 0, stream>>>(x, xn1, xr);
    ContentGCN_5059471475267_attn<<<agrid, ablk, 0, stream>>>(
        xn1, xr, x, 1, W1, a1, y1, 0, xn2);
    // layer 2: V staged from y1 rows; residual = y1
    ContentGCN_5059471475267_attn<<<agrid, ablk, 0, stream>>>(
        xn2, y1, y1, 0, W2, a2, outp, 1, nullptr);
}

// Round 11
// 236.478 us; speedup vs baseline: 1.6395x; 1.6395x over previous
//
#include <hip/hip_runtime.h>

typedef unsigned short u16;
typedef unsigned int   u32;
typedef __bf16 bf16x8 __attribute__((ext_vector_type(8)));   // MFMA A/B (4 VGPRs)
typedef float  f32x16 __attribute__((ext_vector_type(16)));  // MFMA C/D 32x32

#define BH    16
#define NSEQ  4096
#define DIM   64
#define BM    128           // Q rows per block (4 waves x 32 rows, dup across halves)
#define BN    64            // K rows per tile
#define LDP   72            // K/V/W LDS row stride (u16)
#define NTH   32            // K-tiles per half (2 halves x 32 = 64)
#define QTILES (NSEQ / BM)  // 32

// smem carve (u16): sK [2][64*72] | sV [2][64*72] | sW [64*72] | lX f32[256]
#define SK_OFF   0
#define SV_OFF   9216
#define SW_OFF   18432
#define LX_OFF   23040
#define SMEM_U16 23552      // 47104 B
#define HBUF     4608       // one half's K or V buffer (64*72)
// epilogue overlay: outS f32[64][133] at smem base = 34048 B (< SW_OFF*2=36864 B)

#define MFMA __builtin_amdgcn_mfma_f32_32x32x16_bf16

__device__ __forceinline__ float bf2f(u16 u) {
    union { u32 i; float f; } v; v.i = ((u32)u) << 16; return v.f;
}
__device__ __forceinline__ u16 f2bf(float f) {          // true RNE
    union { float f; u32 i; } v; v.f = f;
    u32 r = v.i + 0x7fffu + ((v.i >> 16) & 1u);
    return (u16)(r >> 16);
}
#if __has_builtin(__builtin_amdgcn_exp2f)
__device__ __forceinline__ float exp2_raw(float x) { return __builtin_amdgcn_exp2f(x); }
#else
__device__ __forceinline__ float exp2_raw(float x) {
    float r; asm("v_exp_f32 %0, %1" : "=v"(r) : "v"(x)); return r;
}
#endif
// packed f32->bf16 (RNE), low16 = a, high16 = b
__device__ __forceinline__ u32 cvtpk(float a, float b) {
    u32 r; asm("v_cvt_pk_bf16_f32 %0, %1, %2" : "=v"(r) : "v"(a), "v"(b)); return r;
}
// v_permlane32_swap_b32: a.hi(lanes 32-63) <-> b.lo(lanes 0-31)
__device__ __forceinline__ void plswap(u32& a, u32& b) {
    asm("v_permlane32_swap_b32 %0, %1" : "+v"(a), "+v"(b));
}
// LDS-only barrier: order ds ops across waves WITHOUT draining vmcnt.
__device__ __forceinline__ void lds_barrier() {
    asm volatile("s_waitcnt lgkmcnt(0)\n\ts_barrier" ::: "memory");
}
// load 8 bf16 and scale by s (f32 precision), repack to bf16x8 (hoisted, 1x)
__device__ __forceinline__ bf16x8 ldq_scaled(const u16* p, float s) {
    union { u32 u[4]; bf16x8 v; } r;
#pragma unroll
    for (int i = 0; i < 4; i++)
        r.u[i] = cvtpk(bf2f(p[2*i]) * s, bf2f(p[2*i+1]) * s);
    return r.v;
}

// ---------------------------------------------------------------------------
// prep_norm: read x (fp32) once; write xn = bf16(L2-normalized rows) and
// xr = bf16(raw rows). Pure streaming, no LDS. 1024 blocks.
// ---------------------------------------------------------------------------
__global__ __launch_bounds__(256) void ContentGCN_5059471475267_prepn(
    const float* __restrict__ src, u16* __restrict__ xn, u16* __restrict__ xr)
{
    int gid = blockIdx.x * 256 + threadIdx.x;
    int row = gid >> 2, cg = (gid & 3) * 16;
    size_t base = (size_t)row * DIM + cg;

    float v[16];
    const float4* g = (const float4*)(src + base);
#pragma unroll
    for (int i = 0; i < 4; i++) {
        float4 t = g[i];
        v[4*i] = t.x; v[4*i+1] = t.y; v[4*i+2] = t.z; v[4*i+3] = t.w;
    }
    float ss = 0.f;
#pragma unroll
    for (int d = 0; d < 16; d++) ss += v[d] * v[d];
    ss += __shfl_xor(ss, 1);
    ss += __shfl_xor(ss, 2);                        // full 64-elem row sum
    float n = sqrtf(ss);
    if (n < 1e-12f) n = 1e-12f;                     // F.normalize eps
    float inv = 1.0f / n;

    alignas(16) u16 nb[16], rb[16];
#pragma unroll
    for (int d = 0; d < 16; d++) { nb[d] = f2bf(v[d] * inv); rb[d] = f2bf(v[d]); }
    uint4* gn = (uint4*)(xn + base);
    gn[0] = ((uint4*)nb)[0]; gn[1] = ((uint4*)nb)[1];
    uint4* gr = (uint4*)(xr + base);
    gr[0] = ((uint4*)rb)[0]; gr[1] = ((uint4*)rb)[1];
}

// ---------------------------------------------------------------------------
// attn: 32x32x16 MFMA flash attention, in-register softmax (swapped QK^T +
// cvt_pk/permlane), V transposed during staging via rotation-swizzled
// scalar scatter (n_lds = (n + 16*(d>>4)) & 63; readers use per-lane
// rotated offsets r_k = 16*((k + d>>4)&3)). Cross-kb software pipelining +
// s_setprio around MFMA clusters. Q fragments pre-scaled by `scale` so
// softmax is a bare exp2 (the 2^scale fixed-max factor cancels in O/l).
// This is the verified-best R8 structure: the 2-barrier loop with implicit
// cross-block overlap. Structural overlap variants all regressed:
// V-dbuf (R9: in-order DS drains reads behind staging writes), reg-PV
// (R10: V-fragment live ranges spill to scratch), l-MFMA (R5/R6: +25%
// critical-path MFMA), XCD swizzle / fused transposes (write-path
// amplification). Keep this shape.
// ---------------------------------------------------------------------------
__global__ __launch_bounds__(512, 4) void ContentGCN_5059471475267_attn(
    const u16* __restrict__ xn, const u16* __restrict__ vsrc,
    const void* __restrict__ res, int res_isf,
    const float* __restrict__ Wt, const float* __restrict__ alphap,
    void* __restrict__ outp, int out_isf, u16* __restrict__ xnout)
{
    __shared__ u16 smem[SMEM_U16];
    u16* sK = smem + SK_OFF;
    u16* sV = smem + SV_OFF;
    u16* sW = smem + SW_OFF;
    float* lX = (float*)(smem + LX_OFF);

    int tid  = threadIdx.x;
    int w    = tid >> 6, lane = tid & 63;
    int half = w >> 2,  wv   = w & 3;
    int l31  = lane & 31, hi = lane >> 5;
    int bh   = blockIdx.x >> 5;
    int qt   = blockIdx.x & 31;

    float scale = 1.4426950408889634f / fmaxf(alphap[0], 0.01f);  // exp2 domain

    // stage W once: sW[e*LDP + d] = bf16(W[e][d]); 512 thr cover 64x64
    {
        int rr = tid >> 3, c0 = (tid & 7) * 8;
        const float4* gw = (const float4*)(Wt + rr * DIM + c0);
        float4 t0 = gw[0], t1 = gw[1];
        alignas(16) u16 wb[8];
        wb[0] = f2bf(t0.x); wb[1] = f2bf(t0.y); wb[2] = f2bf(t0.z); wb[3] = f2bf(t0.w);
        wb[4] = f2bf(t1.x); wb[5] = f2bf(t1.y); wb[6] = f2bf(t1.z); wb[7] = f2bf(t1.w);
        *(uint4*)&sW[rr * LDP + c0] = *(const uint4*)wb;
    }

    // Q as MFMA B-fragments, PRE-SCALED by `scale` (col=q=l31, k=d)
    int qrow = qt * BM + wv * 32 + l31;
    const u16* qp = xn + ((size_t)bh * NSEQ + qrow) * DIM + hi * 8;
    bf16x8 bQ0 = ldq_scaled(qp,      scale);
    bf16x8 bQ1 = ldq_scaled(qp + 16, scale);
    bf16x8 bQ2 = ldq_scaled(qp + 32, scale);
    bf16x8 bQ3 = ldq_scaled(qp + 48, scale);

    f32x16 z16;
#pragma unroll
    for (int i = 0; i < 16; i++) z16[i] = 0.f;
    f32x16 OT0 = z16, OT1 = z16;      // O^T: d-blocks 0/1, col=q
    float la0 = 0.f, la1 = 0.f, la2 = 0.f, la3 = 0.f;

    u16* sKh = sK + half * HBUF;
    u16* sVh = sV + half * HBUF;

    int ltid = tid & 255;
    int srow = ltid >> 2, scol = (ltid & 3) * 16;   // per-half staging
    int nl   = (srow + ((ltid & 3) << 4)) & 63;     // rotated n-index

    const u16* pk = xn   + ((size_t)bh * NSEQ + half * (NTH * BN) + srow) * DIM + scol;
    const u16* pv = vsrc + ((size_t)bh * NSEQ + half * (NTH * BN) + srow) * DIM + scol;
    uint4 ck0 = ((const uint4*)pk)[0], ck1 = ((const uint4*)pk)[1];
    uint4 cv0 = ((const uint4*)pv)[0], cv1 = ((const uint4*)pv)[1];
    pk += (size_t)BN * DIM; pv += (size_t)BN * DIM;

    const u16* kB = sKh + l31 * LDP + hi * 8;          // K A-frag base

    // V^T read bases + per-lane rotated n-offsets
    int g  = l31 >> 4;
    int r0 = ((g)     & 3) << 4;
    int r1 = ((g + 1) & 3) << 4;
    int r2 = ((g + 2) & 3) << 4;
    int r3 = ((g + 3) & 3) << 4;
    const u16* vA = sVh + l31 * LDP + hi * 8;          // d-block 0
    const u16* vB = sVh + (32 + l31) * LDP + hi * 8;   // d-block 1

    for (int kt = 0; kt < NTH; kt++) {
        lds_barrier();     // prior tile's LDS reads complete before overwrite
        *(uint4*)&sKh[srow * LDP + scol]     = ck0;
        *(uint4*)&sKh[srow * LDP + scol + 8] = ck1;
        {   // V transpose-staging: 16 scalar writes, rotation-swizzled cols
            alignas(16) u16 vb[16];
            ((uint4*)vb)[0] = cv0; ((uint4*)vb)[1] = cv1;
#pragma unroll
            for (int j = 0; j < 16; j++) sVh[(scol + j) * LDP + nl] = vb[j];
        }
        if (kt + 1 < NTH) {   // prefetch; stays in flight across barrier
            ck0 = ((const uint4*)pk)[0]; ck1 = ((const uint4*)pk)[1];
            cv0 = ((const uint4*)pv)[0]; cv1 = ((const uint4*)pv)[1];
            pk += (size_t)BN * DIM; pv += (size_t)BN * DIM;
        }
        lds_barrier();     // publish K/V tile (no vmcnt drain)

        // --- both S^T batches first (cross-kb ILP: softmax overlaps MFMA) ---
        const u16* kb1 = kB + 32 * LDP;
        f32x16 ST0, ST1;
        __builtin_amdgcn_s_setprio(1);
        ST0 = MFMA(*(const bf16x8*)(kB),       bQ0, z16, 0, 0, 0);
        ST0 = MFMA(*(const bf16x8*)(kB + 16),  bQ1, ST0, 0, 0, 0);
        ST0 = MFMA(*(const bf16x8*)(kB + 32),  bQ2, ST0, 0, 0, 0);
        ST0 = MFMA(*(const bf16x8*)(kB + 48),  bQ3, ST0, 0, 0, 0);
        ST1 = MFMA(*(const bf16x8*)(kb1),      bQ0, z16, 0, 0, 0);
        ST1 = MFMA(*(const bf16x8*)(kb1 + 16), bQ1, ST1, 0, 0, 0);
        ST1 = MFMA(*(const bf16x8*)(kb1 + 32), bQ2, ST1, 0, 0, 0);
        ST1 = MFMA(*(const bf16x8*)(kb1 + 48), bQ3, ST1, 0, 0, 0);
        __builtin_amdgcn_s_setprio(0);

        // --- softmax kb0 (overlaps S(kb1) execution) ---
        {
            float p0  = exp2_raw(ST0[0]);
            float p1  = exp2_raw(ST0[1]);
            float p2  = exp2_raw(ST0[2]);
            float p3  = exp2_raw(ST0[3]);
            float p4  = exp2_raw(ST0[4]);
            float p5  = exp2_raw(ST0[5]);
            float p6  = exp2_raw(ST0[6]);
            float p7  = exp2_raw(ST0[7]);
            float p8  = exp2_raw(ST0[8]);
            float p9  = exp2_raw(ST0[9]);
            float p10 = exp2_raw(ST0[10]);
            float p11 = exp2_raw(ST0[11]);
            float p12 = exp2_raw(ST0[12]);
            float p13 = exp2_raw(ST0[13]);
            float p14 = exp2_raw(ST0[14]);
            float p15 = exp2_raw(ST0[15]);
            u32 w0 = cvtpk(p0,  p1),  w1 = cvtpk(p2,  p3);
            u32 w2 = cvtpk(p4,  p5),  w3 = cvtpk(p6,  p7);
            u32 w4 = cvtpk(p8,  p9),  w5 = cvtpk(p10, p11);
            u32 w6 = cvtpk(p12, p13), w7 = cvtpk(p14, p15);
            plswap(w0, w2); plswap(w1, w3);
            plswap(w4, w6); plswap(w5, w7);
            union { u32 u[4]; bf16x8 v; } bp0, bp1;
            bp0.u[0] = w0; bp0.u[1] = w1; bp0.u[2] = w2; bp0.u[3] = w3;  // k [0,16)
            bp1.u[0] = w4; bp1.u[1] = w5; bp1.u[2] = w6; bp1.u[3] = w7;  // k [16,32)
            __builtin_amdgcn_s_setprio(1);
            OT0 = MFMA(*(const bf16x8*)(vA + r0), bp0.v, OT0, 0, 0, 0);
            OT0 = MFMA(*(const bf16x8*)(vA + r1), bp1.v, OT0, 0, 0, 0);
            OT1 = MFMA(*(const bf16x8*)(vB + r2), bp0.v, OT1, 0, 0, 0);
            OT1 = MFMA(*(const bf16x8*)(vB + r3), bp1.v, OT1, 0, 0, 0);
            __builtin_amdgcn_s_setprio(0);
            la0 += (p0 + p4) + (p8  + p12);
            la1 += (p1 + p5) + (p9  + p13);
            la2 += (p2 + p6) + (p10 + p14);
            la3 += (p3 + p7) + (p11 + p15);
        }

        // --- softmax kb1 (overlaps PV(kb0) execution) ---
        {
            float p0  = exp2_raw(ST1[0]);
            float p1  = exp2_raw(ST1[1]);
            float p2  = exp2_raw(ST1[2]);
            float p3  = exp2_raw(ST1[3]);
            float p4  = exp2_raw(ST1[4]);
            float p5  = exp2_raw(ST1[5]);
            float p6  = exp2_raw(ST1[6]);
            float p7  = exp2_raw(ST1[7]);
            float p8  = exp2_raw(ST1[8]);
            float p9  = exp2_raw(ST1[9]);
            float p10 = exp2_raw(ST1[10]);
            float p11 = exp2_raw(ST1[11]);
            float p12 = exp2_raw(ST1[12]);
            float p13 = exp2_raw(ST1[13]);
            float p14 = exp2_raw(ST1[14]);
            float p15 = exp2_raw(ST1[15]);
            u32 w0 = cvtpk(p0,  p1),  w1 = cvtpk(p2,  p3);
            u32 w2 = cvtpk(p4,  p5),  w3 = cvtpk(p6,  p7);
            u32 w4 = cvtpk(p8,  p9),  w5 = cvtpk(p10, p11);
            u32 w6 = cvtpk(p12, p13), w7 = cvtpk(p14, p15);
            plswap(w0, w2); plswap(w1, w3);
            plswap(w4, w6); plswap(w5, w7);
            union { u32 u[4]; bf16x8 v; } bp0, bp1;
            bp0.u[0] = w0; bp0.u[1] = w1; bp0.u[2] = w2; bp0.u[3] = w3;
            bp1.u[0] = w4; bp1.u[1] = w5; bp1.u[2] = w6; bp1.u[3] = w7;
            __builtin_amdgcn_s_setprio(1);
            OT0 = MFMA(*(const bf16x8*)(vA + r2), bp0.v, OT0, 0, 0, 0);
            OT0 = MFMA(*(const bf16x8*)(vA + r3), bp1.v, OT0, 0, 0, 0);
            OT1 = MFMA(*(const bf16x8*)(vB + r0), bp0.v, OT1, 0, 0, 0);
            OT1 = MFMA(*(const bf16x8*)(vB + r1), bp1.v, OT1, 0, 0, 0);
            __builtin_amdgcn_s_setprio(0);
            la0 += (p0 + p4) + (p8  + p12);
            la1 += (p1 + p5) + (p9  + p13);
            la2 += (p2 + p6) + (p10 + p14);
            la3 += (p3 + p7) + (p11 + p15);
        }
    }

    // ---- l: intra-wave hi/lo merge, then cross-half exchange (tiny) ----
    float lsum = (la0 + la1) + (la2 + la3);
    u32 ja = __float_as_uint(lsum), jb = ja;
    plswap(ja, jb);
    float lfull = __uint_as_float(ja) + __uint_as_float(jb);  // full K-half sum

    __syncthreads();                                  // all loop LDS ops done
    if (lane < 32) lX[w * 32 + l31] = lfull;
    __syncthreads();
    float invl = 1.0f / (lfull + lX[(w ^ 4) * 32 + l31]);

    // ---- av^T -> bf16 B-frags over d-chunks (same cvt_pk+permlane recipe) ----
    union { u32 u[4]; bf16x8 v; } av0, av1, av2, av3;
    {
        u32 x0 = cvtpk(OT0[0]  * invl, OT0[1]  * invl), x1 = cvtpk(OT0[2]  * invl, OT0[3]  * invl);
        u32 x2 = cvtpk(OT0[4]  * invl, OT0[5]  * invl), x3 = cvtpk(OT0[6]  * invl, OT0[7]  * invl);
        u32 x4 = cvtpk(OT0[8]  * invl, OT0[9]  * invl), x5 = cvtpk(OT0[10] * invl, OT0[11] * invl);
        u32 x6 = cvtpk(OT0[12] * invl, OT0[13] * invl), x7 = cvtpk(OT0[14] * invl, OT0[15] * invl);
        plswap(x0, x2); plswap(x1, x3); plswap(x4, x6); plswap(x5, x7);
        av0.u[0] = x0; av0.u[1] = x1; av0.u[2] = x2; av0.u[3] = x3;  // d [0,16)
        av1.u[0] = x4; av1.u[1] = x5; av1.u[2] = x6; av1.u[3] = x7;  // d [16,32)
        u32 y0 = cvtpk(OT1[0]  * invl, OT1[1]  * invl), y1 = cvtpk(OT1[2]  * invl, OT1[3]  * invl);
        u32 y2 = cvtpk(OT1[4]  * invl, OT1[5]  * invl), y3 = cvtpk(OT1[6]  * invl, OT1[7]  * invl);
        u32 y4 = cvtpk(OT1[8]  * invl, OT1[9]  * invl), y5 = cvtpk(OT1[10] * invl, OT1[11] * invl);
        u32 y6 = cvtpk(OT1[12] * invl, OT1[13] * invl), y7 = cvtpk(OT1[14] * invl, OT1[15] * invl);
        plswap(y0, y2); plswap(y1, y3); plswap(y4, y6); plswap(y5, y7);
        av2.u[0] = y0; av2.u[1] = y1; av2.u[2] = y2; av2.u[3] = y3;  // d [32,48)
        av3.u[0] = y4; av3.u[1] = y5; av3.u[2] = y6; av3.u[3] = y7;  // d [48,64)
    }

    // ---- out^T partial = W * av^T (per K-half; linear, so halves sum) ----
    f32x16 R0, R1;
    {
        const u16* w0p = sW + l31 * LDP + hi * 8;          // e-block 0
        const u16* w1p = sW + (32 + l31) * LDP + hi * 8;   // e-block 1
        R0 = MFMA(*(const bf16x8*)(w0p),      av0.v, z16, 0, 0, 0);
        R0 = MFMA(*(const bf16x8*)(w0p + 16), av1.v, R0,  0, 0, 0);
        R0 = MFMA(*(const bf16x8*)(w0p + 32), av2.v, R0,  0, 0, 0);
        R0 = MFMA(*(const bf16x8*)(w0p + 48), av3.v, R0,  0, 0, 0);
        R1 = MFMA(*(const bf16x8*)(w1p),      av0.v, z16, 0, 0, 0);
        R1 = MFMA(*(const bf16x8*)(w1p + 16), av1.v, R1,  0, 0, 0);
        R1 = MFMA(*(const bf16x8*)(w1p + 32), av2.v, R1,  0, 0, 0);
        R1 = MFMA(*(const bf16x8*)(w1p + 48), av3.v, R1,  0, 0, 0);
    }

    // ---- merge halves in f32 LDS outS[e][133] (overlays sK/sV) ----
    float* outS = (float*)smem;
    if (half == 0) {
#pragma unroll
        for (int r = 0; r < 16; r++) {
            int e0 = (r & 3) + 8 * (r >> 2) + 4 * hi;
            outS[e0 * 133 + wv * 32 + l31]        = R0[r];
            outS[(e0 + 32) * 133 + wv * 32 + l31] = R1[r];
        }
    }
    __syncthreads();
    if (half == 1) {
#pragma unroll
        for (int r = 0; r < 16; r++) {
            int e0 = (r & 3) + 8 * (r >> 2) + 4 * hi;
            outS[e0 * 133 + wv * 32 + l31]        += R0[r];
            outS[(e0 + 32) * 133 + wv * 32 + l31] += R1[r];
        }
    }
    __syncthreads();

    // ---- residual + relu + coalesced store (+ fused next-layer normalize) ----
    {
        int q = tid >> 2, c = tid & 3;
        size_t gbase = ((size_t)bh * NSEQ + qt * BM + q) * DIM + c * 16;
        float vv[16];
#pragma unroll
        for (int j = 0; j < 16; j++) vv[j] = outS[(c * 16 + j) * 133 + q];
        if (res_isf) {
            const float4* rp = (const float4*)((const float*)res + gbase);
#pragma unroll
            for (int i = 0; i < 4; i++) {
                float4 t = rp[i];
                vv[4*i] += t.x; vv[4*i+1] += t.y; vv[4*i+2] += t.z; vv[4*i+3] += t.w;
            }
        } else {
            alignas(16) u16 rb[16];
            const uint4* rp = (const uint4*)((const u16*)res + gbase);
            ((uint4*)rb)[0] = rp[0]; ((uint4*)rb)[1] = rp[1];
#pragma unroll
            for (int j = 0; j < 16; j++) vv[j] += bf2f(rb[j]);
        }
#pragma unroll
        for (int j = 0; j < 16; j++) vv[j] = (vv[j] < 0.f) ? 0.f : vv[j];  // NaN-transparent
        if (out_isf) {
            float4* op = (float4*)((float*)outp + gbase);
#pragma unroll
            for (int i = 0; i < 4; i++)
                op[i] = make_float4(vv[4*i], vv[4*i+1], vv[4*i+2], vv[4*i+3]);
        } else {
            alignas(16) u16 ob[16];
#pragma unroll
            for (int j = 0; j < 16; j++) ob[j] = f2bf(vv[j]);
            uint4* op = (uint4*)((u16*)outp + gbase);
            op[0] = ((uint4*)ob)[0]; op[1] = ((uint4*)ob)[1];
        }
        if (xnout) {   // fused next-layer prep: L2-normalize the output row
            float ss = 0.f;
#pragma unroll
            for (int j = 0; j < 16; j++) ss += vv[j] * vv[j];
            ss += __shfl_xor(ss, 1);
            ss += __shfl_xor(ss, 2);                 // 4 lanes/row -> full row
            float n = sqrtf(ss);
            if (n < 1e-12f) n = 1e-12f;
            float inv = 1.0f / n;
            alignas(16) u16 nb[16];
#pragma unroll
            for (int j = 0; j < 16; j++) nb[j] = f2bf(vv[j] * inv);
            uint4* gn = (uint4*)(xnout + gbase);
            gn[0] = ((uint4*)nb)[0]; gn[1] = ((uint4*)nb)[1];
        }
    }
}

extern "C" void kernel_launch(void* const* d_in, const int* in_sizes, int n_in,
                              void* d_out, int out_size, void* d_ws, size_t ws_size,
                              hipStream_t stream) {
    const float* x  = (const float*)d_in[0];
    const float* W1 = (const float*)d_in[1];
    const float* W2 = (const float*)d_in[2];
    const float* a1 = (const float*)d_in[3];
    const float* a2 = (const float*)d_in[4];
    float* outp = (float*)d_out;

    size_t elems = (size_t)BH * NSEQ * DIM;        // 4,194,304
    u16* xn1 = (u16*)d_ws;                         // 8.39 MB normalized (L1)
    u16* xr  = xn1 + elems;                        // 8.39 MB raw bf16 x
    u16* xn2 = xr + elems;                         // 8.39 MB normalized (L2, fused)
    u16* y1  = xn2 + elems;                        // 8.39 MB layer-1 out (bf16)

    dim3 pgrid(1024), pblk(256);
    dim3 agrid(BH * QTILES), ablk(512);

    // layer 1: normalize (xn1) + raw bf16 copy (xr); attn stages V from xr
    ContentGCN_5059471475267_prepn<<<pgrid, pblk, 0, stream>>>(x, xn1, xr);
    ContentGCN_5059471475267_attn<<<agrid, ablk, 0, stream>>>(
        xn1, xr, x, 1, W1, a1, y1, 0, xn2);
    // layer 2: V staged from y1 rows; residual = y1
    ContentGCN_5059471475267_attn<<<agrid, ablk, 0, stream>>>(
        xn2, y1, y1, 0, W2, a2, outp, 1, nullptr);
}

// Round 12
// 229.833 us; speedup vs baseline: 1.6869x; 1.0289x over previous
//
#include <hip/hip_runtime.h>

typedef unsigned short u16;
typedef unsigned int   u32;
typedef __bf16 bf16x8 __attribute__((ext_vector_type(8)));   // MFMA A/B (4 VGPRs)
typedef float  f32x16 __attribute__((ext_vector_type(16)));  // MFMA C/D 32x32

#define BH    16
#define NSEQ  4096
#define DIM   64
#define BM    128           // Q rows per block (4 waves x 32 rows, dup across halves)
#define BN    64            // K rows per tile
#define LDP   72            // K/V/W LDS row stride (u16)
#define NTH   32            // K-tiles per half (2 halves x 32 = 64)
#define QTILES (NSEQ / BM)  // 32

// smem carve (u16): sK [2][64*72] | sV [2][64*72] | sW [64*72] | lX f32[256]
#define SK_OFF   0
#define SV_OFF   9216
#define SW_OFF   18432
#define LX_OFF   23040
#define SMEM_U16 23552      // 47104 B
#define HBUF     4608       // one half's K or V buffer (64*72)
// epilogue overlay: outS f32[64][133] at smem base = 34048 B (< SW_OFF*2=36864 B)

#define MFMA __builtin_amdgcn_mfma_f32_32x32x16_bf16

__device__ __forceinline__ float bf2f(u16 u) {
    union { u32 i; float f; } v; v.i = ((u32)u) << 16; return v.f;
}
__device__ __forceinline__ u16 f2bf(float f) {          // true RNE
    union { float f; u32 i; } v; v.f = f;
    u32 r = v.i + 0x7fffu + ((v.i >> 16) & 1u);
    return (u16)(r >> 16);
}
#if __has_builtin(__builtin_amdgcn_exp2f)
__device__ __forceinline__ float exp2_raw(float x) { return __builtin_amdgcn_exp2f(x); }
#else
__device__ __forceinline__ float exp2_raw(float x) {
    float r; asm("v_exp_f32 %0, %1" : "=v"(r) : "v"(x)); return r;
}
#endif
// packed f32->bf16 (RNE), low16 = a, high16 = b
__device__ __forceinline__ u32 cvtpk(float a, float b) {
    u32 r; asm("v_cvt_pk_bf16_f32 %0, %1, %2" : "=v"(r) : "v"(a), "v"(b)); return r;
}
// v_permlane32_swap_b32: a.hi(lanes 32-63) <-> b.lo(lanes 0-31)
__device__ __forceinline__ void plswap(u32& a, u32& b) {
    asm("v_permlane32_swap_b32 %0, %1" : "+v"(a), "+v"(b));
}
// LDS-only barrier: order ds ops across waves WITHOUT draining vmcnt.
__device__ __forceinline__ void lds_barrier() {
    asm volatile("s_waitcnt lgkmcnt(0)\n\ts_barrier" ::: "memory");
}
// load 8 bf16 and scale by s (f32 precision), repack to bf16x8 (hoisted, 1x)
__device__ __forceinline__ bf16x8 ldq_scaled(const u16* p, float s) {
    union { u32 u[4]; bf16x8 v; } r;
#pragma unroll
    for (int i = 0; i < 4; i++)
        r.u[i] = cvtpk(bf2f(p[2*i]) * s, bf2f(p[2*i+1]) * s);
    return r.v;
}

// ---------------------------------------------------------------------------
// prep_norm: read x (fp32) once; write xn = bf16(L2-normalized rows) and
// xr = bf16(raw rows). Pure streaming, no LDS. 1024 blocks.
// ---------------------------------------------------------------------------
__global__ __launch_bounds__(256) void ContentGCN_5059471475267_prepn(
    const float* __restrict__ src, u16* __restrict__ xn, u16* __restrict__ xr)
{
    int gid = blockIdx.x * 256 + threadIdx.x;
    int row = gid >> 2, cg = (gid & 3) * 16;
    size_t base = (size_t)row * DIM + cg;

    float v[16];
    const float4* g = (const float4*)(src + base);
#pragma unroll
    for (int i = 0; i < 4; i++) {
        float4 t = g[i];
        v[4*i] = t.x; v[4*i+1] = t.y; v[4*i+2] = t.z; v[4*i+3] = t.w;
    }
    float ss = 0.f;
#pragma unroll
    for (int d = 0; d < 16; d++) ss += v[d] * v[d];
    ss += __shfl_xor(ss, 1);
    ss += __shfl_xor(ss, 2);                        // full 64-elem row sum
    float n = sqrtf(ss);
    if (n < 1e-12f) n = 1e-12f;                     // F.normalize eps
    float inv = 1.0f / n;

    alignas(16) u16 nb[16], rb[16];
#pragma unroll
    for (int d = 0; d < 16; d++) { nb[d] = f2bf(v[d] * inv); rb[d] = f2bf(v[d]); }
    uint4* gn = (uint4*)(xn + base);
    gn[0] = ((uint4*)nb)[0]; gn[1] = ((uint4*)nb)[1];
    uint4* gr = (uint4*)(xr + base);
    gr[0] = ((uint4*)rb)[0]; gr[1] = ((uint4*)rb)[1];
}

// ---------------------------------------------------------------------------
// attn: 32x32x16 MFMA flash attention, in-register softmax (swapped QK^T +
// cvt_pk/permlane), V transposed during staging via rotation-swizzled
// scatter. R12 change: V staging is ROW-PAIR based — each thread loads two
// adjacent V rows (n,n+1) x 8 d (two coalesced 16B loads), packs
// (V[n][d], V[n+1][d]) into a u32 and writes 8x ds_write_b32 (halves the
// V-staging DS ops vs 16x b16; bank-uniform: bank = (4j+rp+8(c>>1))%32,
// 2 lanes/bank = free; swizzle ring never wraps since nl0 is even).
// Read-side mapping unchanged: n_lds = (n + 16*(d>>4)) & 63, readers use
// per-lane rotated offsets r_k = 16*((k + d>>4)&3).
// Q pre-scaled by `scale` so softmax is a bare exp2 (2^scale cancels in O/l).
// Verified-best R8 2-barrier loop otherwise (V-dbuf/reg-PV/l-MFMA/XCD-swizzle
// /fused-transposes all regressed with diagnosed mechanisms — keep shape).
// ---------------------------------------------------------------------------
__global__ __launch_bounds__(512, 4) void ContentGCN_5059471475267_attn(
    const u16* __restrict__ xn, const u16* __restrict__ vsrc,
    const void* __restrict__ res, int res_isf,
    const float* __restrict__ Wt, const float* __restrict__ alphap,
    void* __restrict__ outp, int out_isf, u16* __restrict__ xnout)
{
    __shared__ u16 smem[SMEM_U16];
    u16* sK = smem + SK_OFF;
    u16* sV = smem + SV_OFF;
    u16* sW = smem + SW_OFF;
    float* lX = (float*)(smem + LX_OFF);

    int tid  = threadIdx.x;
    int w    = tid >> 6, lane = tid & 63;
    int half = w >> 2,  wv   = w & 3;
    int l31  = lane & 31, hi = lane >> 5;
    int bh   = blockIdx.x >> 5;
    int qt   = blockIdx.x & 31;

    float scale = 1.4426950408889634f / fmaxf(alphap[0], 0.01f);  // exp2 domain

    // stage W once: sW[e*LDP + d] = bf16(W[e][d]); 512 thr cover 64x64
    {
        int rr = tid >> 3, c0 = (tid & 7) * 8;
        const float4* gw = (const float4*)(Wt + rr * DIM + c0);
        float4 t0 = gw[0], t1 = gw[1];
        alignas(16) u16 wb[8];
        wb[0] = f2bf(t0.x); wb[1] = f2bf(t0.y); wb[2] = f2bf(t0.z); wb[3] = f2bf(t0.w);
        wb[4] = f2bf(t1.x); wb[5] = f2bf(t1.y); wb[6] = f2bf(t1.z); wb[7] = f2bf(t1.w);
        *(uint4*)&sW[rr * LDP + c0] = *(const uint4*)wb;
    }

    // Q as MFMA B-fragments, PRE-SCALED by `scale` (col=q=l31, k=d)
    int qrow = qt * BM + wv * 32 + l31;
    const u16* qp = xn + ((size_t)bh * NSEQ + qrow) * DIM + hi * 8;
    bf16x8 bQ0 = ldq_scaled(qp,      scale);
    bf16x8 bQ1 = ldq_scaled(qp + 16, scale);
    bf16x8 bQ2 = ldq_scaled(qp + 32, scale);
    bf16x8 bQ3 = ldq_scaled(qp + 48, scale);

    f32x16 z16;
#pragma unroll
    for (int i = 0; i < 16; i++) z16[i] = 0.f;
    f32x16 OT0 = z16, OT1 = z16;      // O^T: d-blocks 0/1, col=q
    float la0 = 0.f, la1 = 0.f, la2 = 0.f, la3 = 0.f;

    u16* sKh = sK + half * HBUF;
    u16* sVh = sV + half * HBUF;

    int ltid = tid & 255;
    int srow = ltid >> 2, scol = (ltid & 3) * 16;   // per-half K staging
    // V row-pair staging: rp = ltid>>3 (rows 2rp,2rp+1), c = ltid&7 (d 8c..8c+7)
    int vrp = ltid >> 3, vc = ltid & 7;
    int vn0 = vrp * 2;
    int vd0 = vc * 8;
    int nl0 = (vn0 + (((vd0 >> 4)) << 4)) & 63;     // rotated n (even, no wrap)

    const u16* pk = xn   + ((size_t)bh * NSEQ + half * (NTH * BN) + srow) * DIM + scol;
    const u16* pv = vsrc + ((size_t)bh * NSEQ + half * (NTH * BN) + vn0) * DIM + vd0;
    uint4 ck0 = ((const uint4*)pk)[0], ck1 = ((const uint4*)pk)[1];
    uint4 cv0 = ((const uint4*)pv)[0];              // row n0: 8 bf16
    uint4 cv1 = *(const uint4*)(pv + DIM);          // row n1: 8 bf16
    pk += (size_t)BN * DIM; pv += (size_t)BN * DIM;

    const u16* kB = sKh + l31 * LDP + hi * 8;          // K A-frag base

    // V^T read bases + per-lane rotated n-offsets
    int g  = l31 >> 4;
    int r0 = ((g)     & 3) << 4;
    int r1 = ((g + 1) & 3) << 4;
    int r2 = ((g + 2) & 3) << 4;
    int r3 = ((g + 3) & 3) << 4;
    const u16* vA = sVh + l31 * LDP + hi * 8;          // d-block 0
    const u16* vB = sVh + (32 + l31) * LDP + hi * 8;   // d-block 1

    for (int kt = 0; kt < NTH; kt++) {
        lds_barrier();     // prior tile's LDS reads complete before overwrite
        *(uint4*)&sKh[srow * LDP + scol]     = ck0;
        *(uint4*)&sKh[srow * LDP + scol + 8] = ck1;
        {   // V transpose-staging: 8x b32 (n-pair packed), rotation-swizzled
            alignas(16) u16 a0[8], a1[8];
            *(uint4*)a0 = cv0; *(uint4*)a1 = cv1;
#pragma unroll
            for (int j = 0; j < 8; j++)
                *(u32*)&sVh[(vd0 + j) * LDP + nl0] = (u32)a0[j] | ((u32)a1[j] << 16);
        }
        if (kt + 1 < NTH) {   // prefetch; stays in flight across barrier
            ck0 = ((const uint4*)pk)[0]; ck1 = ((const uint4*)pk)[1];
            cv0 = ((const uint4*)pv)[0]; cv1 = *(const uint4*)(pv + DIM);
            pk += (size_t)BN * DIM; pv += (size_t)BN * DIM;
        }
        lds_barrier();     // publish K/V tile (no vmcnt drain)

        // --- both S^T batches first (cross-kb ILP: softmax overlaps MFMA) ---
        const u16* kb1 = kB + 32 * LDP;
        f32x16 ST0, ST1;
        __builtin_amdgcn_s_setprio(1);
        ST0 = MFMA(*(const bf16x8*)(kB),       bQ0, z16, 0, 0, 0);
        ST0 = MFMA(*(const bf16x8*)(kB + 16),  bQ1, ST0, 0, 0, 0);
        ST0 = MFMA(*(const bf16x8*)(kB + 32),  bQ2, ST0, 0, 0, 0);
        ST0 = MFMA(*(const bf16x8*)(kB + 48),  bQ3, ST0, 0, 0, 0);
        ST1 = MFMA(*(const bf16x8*)(kb1),      bQ0, z16, 0, 0, 0);
        ST1 = MFMA(*(const bf16x8*)(kb1 + 16), bQ1, ST1, 0, 0, 0);
        ST1 = MFMA(*(const bf16x8*)(kb1 + 32), bQ2, ST1, 0, 0, 0);
        ST1 = MFMA(*(const bf16x8*)(kb1 + 48), bQ3, ST1, 0, 0, 0);
        __builtin_amdgcn_s_setprio(0);

        // --- softmax kb0 (overlaps S(kb1) execution) ---
        {
            float p0  = exp2_raw(ST0[0]);
            float p1  = exp2_raw(ST0[1]);
            float p2  = exp2_raw(ST0[2]);
            float p3  = exp2_raw(ST0[3]);
            float p4  = exp2_raw(ST0[4]);
            float p5  = exp2_raw(ST0[5]);
            float p6  = exp2_raw(ST0[6]);
            float p7  = exp2_raw(ST0[7]);
            float p8  = exp2_raw(ST0[8]);
            float p9  = exp2_raw(ST0[9]);
            float p10 = exp2_raw(ST0[10]);
            float p11 = exp2_raw(ST0[11]);
            float p12 = exp2_raw(ST0[12]);
            float p13 = exp2_raw(ST0[13]);
            float p14 = exp2_raw(ST0[14]);
            float p15 = exp2_raw(ST0[15]);
            u32 w0 = cvtpk(p0,  p1),  w1 = cvtpk(p2,  p3);
            u32 w2 = cvtpk(p4,  p5),  w3 = cvtpk(p6,  p7);
            u32 w4 = cvtpk(p8,  p9),  w5 = cvtpk(p10, p11);
            u32 w6 = cvtpk(p12, p13), w7 = cvtpk(p14, p15);
            plswap(w0, w2); plswap(w1, w3);
            plswap(w4, w6); plswap(w5, w7);
            union { u32 u[4]; bf16x8 v; } bp0, bp1;
            bp0.u[0] = w0; bp0.u[1] = w1; bp0.u[2] = w2; bp0.u[3] = w3;  // k [0,16)
            bp1.u[0] = w4; bp1.u[1] = w5; bp1.u[2] = w6; bp1.u[3] = w7;  // k [16,32)
            __builtin_amdgcn_s_setprio(1);
            OT0 = MFMA(*(const bf16x8*)(vA + r0), bp0.v, OT0, 0, 0, 0);
            OT0 = MFMA(*(const bf16x8*)(vA + r1), bp1.v, OT0, 0, 0, 0);
            OT1 = MFMA(*(const bf16x8*)(vB + r2), bp0.v, OT1, 0, 0, 0);
            OT1 = MFMA(*(const bf16x8*)(vB + r3), bp1.v, OT1, 0, 0, 0);
            __builtin_amdgcn_s_setprio(0);
            la0 += (p0 + p4) + (p8  + p12);
            la1 += (p1 + p5) + (p9  + p13);
            la2 += (p2 + p6) + (p10 + p14);
            la3 += (p3 + p7) + (p11 + p15);
        }

        // --- softmax kb1 (overlaps PV(kb0) execution) ---
        {
            float p0  = exp2_raw(ST1[0]);
            float p1  = exp2_raw(ST1[1]);
            float p2  = exp2_raw(ST1[2]);
            float p3  = exp2_raw(ST1[3]);
            float p4  = exp2_raw(ST1[4]);
            float p5  = exp2_raw(ST1[5]);
            float p6  = exp2_raw(ST1[6]);
            float p7  = exp2_raw(ST1[7]);
            float p8  = exp2_raw(ST1[8]);
            float p9  = exp2_raw(ST1[9]);
            float p10 = exp2_raw(ST1[10]);
            float p11 = exp2_raw(ST1[11]);
            float p12 = exp2_raw(ST1[12]);
            float p13 = exp2_raw(ST1[13]);
            float p14 = exp2_raw(ST1[14]);
            float p15 = exp2_raw(ST1[15]);
            u32 w0 = cvtpk(p0,  p1),  w1 = cvtpk(p2,  p3);
            u32 w2 = cvtpk(p4,  p5),  w3 = cvtpk(p6,  p7);
            u32 w4 = cvtpk(p8,  p9),  w5 = cvtpk(p10, p11);
            u32 w6 = cvtpk(p12, p13), w7 = cvtpk(p14, p15);
            plswap(w0, w2); plswap(w1, w3);
            plswap(w4, w6); plswap(w5, w7);
            union { u32 u[4]; bf16x8 v; } bp0, bp1;
            bp0.u[0] = w0; bp0.u[1] = w1; bp0.u[2] = w2; bp0.u[3] = w3;
            bp1.u[0] = w4; bp1.u[1] = w5; bp1.u[2] = w6; bp1.u[3] = w7;
            __builtin_amdgcn_s_setprio(1);
            OT0 = MFMA(*(const bf16x8*)(vA + r2), bp0.v, OT0, 0, 0, 0);
            OT0 = MFMA(*(const bf16x8*)(vA + r3), bp1.v, OT0, 0, 0, 0);
            OT1 = MFMA(*(const bf16x8*)(vB + r0), bp0.v, OT1, 0, 0, 0);
            OT1 = MFMA(*(const bf16x8*)(vB + r1), bp1.v, OT1, 0, 0, 0);
            __builtin_amdgcn_s_setprio(0);
            la0 += (p0 + p4) + (p8  + p12);
            la1 += (p1 + p5) + (p9  + p13);
            la2 += (p2 + p6) + (p10 + p14);
            la3 += (p3 + p7) + (p11 + p15);
        }
    }

    // ---- l: intra-wave hi/lo merge, then cross-half exchange (tiny) ----
    float lsum = (la0 + la1) + (la2 + la3);
    u32 ja = __float_as_uint(lsum), jb = ja;
    plswap(ja, jb);
    float lfull = __uint_as_float(ja) + __uint_as_float(jb);  // full K-half sum

    __syncthreads();                                  // all loop LDS ops done
    if (lane < 32) lX[w * 32 + l31] = lfull;
    __syncthreads();
    float invl = 1.0f / (lfull + lX[(w ^ 4) * 32 + l31]);

    // ---- av^T -> bf16 B-frags over d-chunks (same cvt_pk+permlane recipe) ----
    union { u32 u[4]; bf16x8 v; } av0, av1, av2, av3;
    {
        u32 x0 = cvtpk(OT0[0]  * invl, OT0[1]  * invl), x1 = cvtpk(OT0[2]  * invl, OT0[3]  * invl);
        u32 x2 = cvtpk(OT0[4]  * invl, OT0[5]  * invl), x3 = cvtpk(OT0[6]  * invl, OT0[7]  * invl);
        u32 x4 = cvtpk(OT0[8]  * invl, OT0[9]  * invl), x5 = cvtpk(OT0[10] * invl, OT0[11] * invl);
        u32 x6 = cvtpk(OT0[12] * invl, OT0[13] * invl), x7 = cvtpk(OT0[14] * invl, OT0[15] * invl);
        plswap(x0, x2); plswap(x1, x3); plswap(x4, x6); plswap(x5, x7);
        av0.u[0] = x0; av0.u[1] = x1; av0.u[2] = x2; av0.u[3] = x3;  // d [0,16)
        av1.u[0] = x4; av1.u[1] = x5; av1.u[2] = x6; av1.u[3] = x7;  // d [16,32)
        u32 y0 = cvtpk(OT1[0]  * invl, OT1[1]  * invl), y1 = cvtpk(OT1[2]  * invl, OT1[3]  * invl);
        u32 y2 = cvtpk(OT1[4]  * invl, OT1[5]  * invl), y3 = cvtpk(OT1[6]  * invl, OT1[7]  * invl);
        u32 y4 = cvtpk(OT1[8]  * invl, OT1[9]  * invl), y5 = cvtpk(OT1[10] * invl, OT1[11] * invl);
        u32 y6 = cvtpk(OT1[12] * invl, OT1[13] * invl), y7 = cvtpk(OT1[14] * invl, OT1[15] * invl);
        plswap(y0, y2); plswap(y1, y3); plswap(y4, y6); plswap(y5, y7);
        av2.u[0] = y0; av2.u[1] = y1; av2.u[2] = y2; av2.u[3] = y3;  // d [32,48)
        av3.u[0] = y4; av3.u[1] = y5; av3.u[2] = y6; av3.u[3] = y7;  // d [48,64)
    }

    // ---- out^T partial = W * av^T (per K-half; linear, so halves sum) ----
    f32x16 R0, R1;
    {
        const u16* w0p = sW + l31 * LDP + hi * 8;          // e-block 0
        const u16* w1p = sW + (32 + l31) * LDP + hi * 8;   // e-block 1
        R0 = MFMA(*(const bf16x8*)(w0p),      av0.v, z16, 0, 0, 0);
        R0 = MFMA(*(const bf16x8*)(w0p + 16), av1.v, R0,  0, 0, 0);
        R0 = MFMA(*(const bf16x8*)(w0p + 32), av2.v, R0,  0, 0, 0);
        R0 = MFMA(*(const bf16x8*)(w0p + 48), av3.v, R0,  0, 0, 0);
        R1 = MFMA(*(const bf16x8*)(w1p),      av0.v, z16, 0, 0, 0);
        R1 = MFMA(*(const bf16x8*)(w1p + 16), av1.v, R1,  0, 0, 0);
        R1 = MFMA(*(const bf16x8*)(w1p + 32), av2.v, R1,  0, 0, 0);
        R1 = MFMA(*(const bf16x8*)(w1p + 48), av3.v, R1,  0, 0, 0);
    }

    // ---- merge halves in f32 LDS outS[e][133] (overlays sK/sV) ----
    float* outS = (float*)smem;
    if (half == 0) {
#pragma unroll
        for (int r = 0; r < 16; r++) {
            int e0 = (r & 3) + 8 * (r >> 2) + 4 * hi;
            outS[e0 * 133 + wv * 32 + l31]        = R0[r];
            outS[(e0 + 32) * 133 + wv * 32 + l31] = R1[r];
        }
    }
    __syncthreads();
    if (half == 1) {
#pragma unroll
        for (int r = 0; r < 16; r++) {
            int e0 = (r & 3) + 8 * (r >> 2) + 4 * hi;
            outS[e0 * 133 + wv * 32 + l31]        += R0[r];
            outS[(e0 + 32) * 133 + wv * 32 + l31] += R1[r];
        }
    }
    __syncthreads();

    // ---- residual + relu + coalesced store (+ fused next-layer normalize) ----
    {
        int q = tid >> 2, c = tid & 3;
        size_t gbase = ((size_t)bh * NSEQ + qt * BM + q) * DIM + c * 16;
        float vv[16];
#pragma unroll
        for (int j = 0; j < 16; j++) vv[j] = outS[(c * 16 + j) * 133 + q];
        if (res_isf) {
            const float4* rp = (const float4*)((const float*)res + gbase);
#pragma unroll
            for (int i = 0; i < 4; i++) {
                float4 t = rp[i];
                vv[4*i] += t.x; vv[4*i+1] += t.y; vv[4*i+2] += t.z; vv[4*i+3] += t.w;
            }
        } else {
            alignas(16) u16 rb[16];
            const uint4* rp = (const uint4*)((const u16*)res + gbase);
            ((uint4*)rb)[0] = rp[0]; ((uint4*)rb)[1] = rp[1];
#pragma unroll
            for (int j = 0; j < 16; j++) vv[j] += bf2f(rb[j]);
        }
#pragma unroll
        for (int j = 0; j < 16; j++) vv[j] = (vv[j] < 0.f) ? 0.f : vv[j];  // NaN-transparent
        if (out_isf) {
            float4* op = (float4*)((float*)outp + gbase);
#pragma unroll
            for (int i = 0; i < 4; i++)
                op[i] = make_float4(vv[4*i], vv[4*i+1], vv[4*i+2], vv[4*i+3]);
        } else {
            alignas(16) u16 ob[16];
#pragma unroll
            for (int j = 0; j < 16; j++) ob[j] = f2bf(vv[j]);
            uint4* op = (uint4*)((u16*)outp + gbase);
            op[0] = ((uint4*)ob)[0]; op[1] = ((uint4*)ob)[1];
        }
        if (xnout) {   // fused next-layer prep: L2-normalize the output row
            float ss = 0.f;
#pragma unroll
            for (int j = 0; j < 16; j++) ss += vv[j] * vv[j];
            ss += __shfl_xor(ss, 1);
            ss += __shfl_xor(ss, 2);                 // 4 lanes/row -> full row
            float n = sqrtf(ss);
            if (n < 1e-12f) n = 1e-12f;
            float inv = 1.0f / n;
            alignas(16) u16 nb[16];
#pragma unroll
            for (int j = 0; j < 16; j++) nb[j] = f2bf(vv[j] * inv);
            uint4* gn = (uint4*)(xnout + gbase);
            gn[0] = ((uint4*)nb)[0]; gn[1] = ((uint4*)nb)[1];
        }
    }
}

extern "C" void kernel_launch(void* const* d_in, const int* in_sizes, int n_in,
                              void* d_out, int out_size, void* d_ws, size_t ws_size,
                              hipStream_t stream) {
    const float* x  = (const float*)d_in[0];
    const float* W1 = (const float*)d_in[1];
    const float* W2 = (const float*)d_in[2];
    const float* a1 = (const float*)d_in[3];
    const float* a2 = (const float*)d_in[4];
    float* outp = (float*)d_out;

    size_t elems = (size_t)BH * NSEQ * DIM;        // 4,194,304
    u16* xn1 = (u16*)d_ws;                         // 8.39 MB normalized (L1)
    u16* xr  = xn1 + elems;                        // 8.39 MB raw bf16 x
    u16* xn2 = xr + elems;                         // 8.39 MB normalized (L2, fused)
    u16* y1  = xn2 + elems;                        // 8.39 MB layer-1 out (bf16)

    dim3 pgrid(1024), pblk(256);
    dim3 agrid(BH * QTILES), ablk(512);

    // layer 1: normalize (xn1) + raw bf16 copy (xr); attn stages V from xr
    ContentGCN_5059471475267_prepn<<<pgrid, pblk, 0, stream>>>(x, xn1, xr);
    ContentGCN_5059471475267_attn<<<agrid, ablk, 0, stream>>>(
        xn1, xr, x, 1, W1, a1, y1, 0, xn2);
    // layer 2: V staged from y1 rows; residual = y1
    ContentGCN_5059471475267_attn<<<agrid, ablk, 0, stream>>>(
        xn2, y1, y1, 0, W2, a2, outp, 1, nullptr);
}